// Round 1
// baseline (16138.736 us; speedup 1.0000x reference)
//
#include <hip/hip_runtime.h>
#include <math.h>

// Problem constants
#define B_    32
#define T_    1000
#define E_    512
#define D_    1024
#define A_    512
#define C_    10
#define F_    100
#define ODIM_ 5000
#define OLEN_ 101
#define SOS_  4998

// ---- workspace layout (float offsets) ----
#define OFF_PRE   0u
#define N_PRE     (32u*1000u*512u)          // 16,384,000
#define OFF_DEC   (OFF_PRE + N_PRE)         // [B][A]
#define N_DEC     (32u*512u)
#define OFF_CONV  (OFF_DEC + N_DEC)         // [B][C][T]
#define N_CONVB   (32u*10u*1000u)
#define OFF_EB    (OFF_CONV + N_CONVB)      // [B][T] energies
#define N_EB      (32u*1000u)
#define OFF_AW    (OFF_EB + N_EB)           // [B][T] attention weights
#define OFF_CTX   (OFF_AW + N_EB)           // [B][E]
#define N_CTX     (32u*512u)
#define OFF_GP    (OFF_CTX + N_CTX)         // [10][B][4096] gate partials
#define N_GP      (10u*32u*4096u)
#define OFF_Z     (OFF_GP + N_GP)           // [B][D]
#define N_Z       (32u*1024u)
#define OFF_C     (OFF_Z + N_Z)             // [B][D]
#define OFF_ZALL  (OFF_C + N_Z)             // [101][B][D]
// total = 21,485,056 floats = 85.9 MB

// ---------------- init: z=0, c=0, aw=1/T ----------------
__global__ __launch_bounds__(256) void k_init(float* ws) {
    int i = blockIdx.x * 256 + threadIdx.x;
    if (i < (int)N_Z) { ws[OFF_Z + i] = 0.f; ws[OFF_C + i] = 0.f; }
    if (i < (int)N_EB) ws[OFF_AW + i] = 1.0f / (float)T_;
}

// ---------------- pre = hpad @ w_enc^T + b_enc ----------------
// M=32000, N=512, K=512. 64x64 tiles, 4x4 per thread.
__global__ __launch_bounds__(256) void k_pre(const float* __restrict__ hp,
                                             const float* __restrict__ we,
                                             const float* __restrict__ be,
                                             float* __restrict__ pre) {
    __shared__ float As[64][68];
    __shared__ float Bs[64][68];
    int m0 = blockIdx.y * 64, n0 = blockIdx.x * 64;
    int tid = threadIdx.x;
    int tr = tid >> 4, tc = tid & 15;
    float acc[4][4] = {};
    for (int k0 = 0; k0 < 512; k0 += 64) {
        for (int i = tid; i < 1024; i += 256) {
            int m = i >> 4, kq = (i & 15) << 2;
            float4 v = *(const float4*)&hp[(size_t)(m0 + m) * 512 + k0 + kq];
            As[kq + 0][m] = v.x; As[kq + 1][m] = v.y; As[kq + 2][m] = v.z; As[kq + 3][m] = v.w;
            float4 w = *(const float4*)&we[(size_t)(n0 + m) * 512 + k0 + kq];
            Bs[kq + 0][m] = w.x; Bs[kq + 1][m] = w.y; Bs[kq + 2][m] = w.z; Bs[kq + 3][m] = w.w;
        }
        __syncthreads();
        #pragma unroll 16
        for (int kk = 0; kk < 64; ++kk) {
            float4 av = *(const float4*)&As[kk][tr << 2];
            float4 bv = *(const float4*)&Bs[kk][tc << 2];
            float a[4] = {av.x, av.y, av.z, av.w};
            float b[4] = {bv.x, bv.y, bv.z, bv.w};
            #pragma unroll
            for (int i = 0; i < 4; i++)
                #pragma unroll
                for (int j = 0; j < 4; j++) acc[i][j] += a[i] * b[j];
        }
        __syncthreads();
    }
    #pragma unroll
    for (int i = 0; i < 4; i++) {
        int m = m0 + (tr << 2) + i;
        int n = n0 + (tc << 2);
        float4 o;
        o.x = acc[i][0] + be[n + 0];
        o.y = acc[i][1] + be[n + 1];
        o.z = acc[i][2] + be[n + 2];
        o.w = acc[i][3] + be[n + 3];
        *(float4*)&pre[(size_t)m * 512 + n] = o;
    }
}

// ---------------- per-step: dec = z @ w_dec^T ; conv ----------------
__global__ __launch_bounds__(256) void k_prep(const float* __restrict__ wdec,
                                              const float* __restrict__ wconv,
                                              float* ws) {
    int tid = threadIdx.x;
    if (blockIdx.x < 4096) {
        // dec: one wave per output (b,a), lanes over d
        int gw = blockIdx.x * 4 + (tid >> 6);
        int lane = tid & 63;
        int b = gw >> 9, a = gw & 511;
        const float* wr = wdec + (size_t)a * 1024;
        const float* zr = ws + OFF_Z + b * 1024;
        float acc = 0.f;
        #pragma unroll
        for (int i = 0; i < 16; i++) acc += wr[i * 64 + lane] * zr[i * 64 + lane];
        #pragma unroll
        for (int off = 32; off > 0; off >>= 1) acc += __shfl_xor(acc, off, 64);
        if (lane == 0) ws[OFF_DEC + b * 512 + a] = acc;
    } else {
        // conv: one thread per (b,c,t)
        int idx = (blockIdx.x - 4096) * 256 + tid;
        if (idx < 320000) {
            int b = idx / 10000;
            int r = idx - b * 10000;
            int c = r / 1000;
            int t = r - c * 1000;
            const float* ar = ws + OFF_AW + b * 1000;
            const float* wc = wconv + c * 201;
            int jlo = (100 - t) > 0 ? (100 - t) : 0;
            int jhi = (1100 - t) < 201 ? (1100 - t) : 201;
            float acc = 0.f;
            for (int j = jlo; j < jhi; ++j) acc += ar[t + j - 100] * wc[j];
            ws[OFF_CONV + (b * 10 + c) * 1000 + t] = acc;
        }
    }
}

// ---------------- per-step energy e[b,t] ----------------
// one wave per (b,t); lanes over a
__global__ __launch_bounds__(256) void k_energy(const float* __restrict__ watt,
                                                const float* __restrict__ gvec,
                                                const float* __restrict__ bg,
                                                float* ws) {
    int gw = blockIdx.x * 4 + (threadIdx.x >> 6); // 0..31999
    int lane = threadIdx.x & 63;
    int b = gw / 1000, t = gw - b * 1000;
    float cv[10];
    const float* cb = ws + OFF_CONV + b * 10000 + t;
    #pragma unroll
    for (int c = 0; c < 10; c++) cv[c] = cb[c * 1000];
    const float* pr = ws + OFF_PRE + (size_t)(b * 1000 + t) * 512;
    const float* dc = ws + OFF_DEC + b * 512;
    float acc = 0.f;
    #pragma unroll
    for (int i = 0; i < 8; i++) {
        int a = i * 64 + lane;
        float att = 0.f;
        #pragma unroll
        for (int c = 0; c < 10; c++) att += cv[c] * watt[a * 10 + c];
        float v = tanhf(pr[a] + att + dc[a]);
        acc += v * gvec[a];
    }
    #pragma unroll
    for (int off = 32; off > 0; off >>= 1) acc += __shfl_xor(acc, off, 64);
    if (lane == 0) ws[OFF_EB + gw] = acc + bg[0];
}

// ---------------- per-step softmax over T (+ zero ctx) ----------------
__global__ __launch_bounds__(256) void k_softmax(float* ws) {
    int b = blockIdx.x, tid = threadIdx.x;
    ws[OFF_CTX + b * 512 + tid] = 0.f;
    ws[OFF_CTX + b * 512 + 256 + tid] = 0.f;
    __shared__ float red[256];
    const float* e = ws + OFF_EB + b * 1000;
    float s[4];
    float m = -1e30f;
    #pragma unroll
    for (int j = 0; j < 4; j++) {
        int t = tid + j * 256;
        s[j] = (t < 1000) ? 2.0f * e[t] : -1e30f;
        m = fmaxf(m, s[j]);
    }
    red[tid] = m; __syncthreads();
    for (int off = 128; off > 0; off >>= 1) {
        if (tid < off) red[tid] = fmaxf(red[tid], red[tid + off]);
        __syncthreads();
    }
    m = red[0]; __syncthreads();
    float p[4], sum = 0.f;
    #pragma unroll
    for (int j = 0; j < 4; j++) {
        int t = tid + j * 256;
        p[j] = (t < 1000) ? expf(s[j] - m) : 0.f;
        sum += p[j];
    }
    red[tid] = sum; __syncthreads();
    for (int off = 128; off > 0; off >>= 1) {
        if (tid < off) red[tid] += red[tid + off];
        __syncthreads();
    }
    float inv = 1.0f / red[0];
    #pragma unroll
    for (int j = 0; j < 4; j++) {
        int t = tid + j * 256;
        if (t < 1000) ws[OFF_AW + b * 1000 + t] = p[j] * inv;
    }
}

// ---------------- per-step ctx[b,e] = sum_t aw[b,t]*hpad[b,t,e] ----------------
// grid = (b 32) x (tsplit 8); block 512 threads over e
__global__ __launch_bounds__(512) void k_ctx(const float* __restrict__ hp, float* ws) {
    int b = blockIdx.x >> 3, ts = blockIdx.x & 7;
    int e = threadIdx.x;
    const float* awr = ws + OFF_AW + b * 1000;
    int t0 = ts * 125;
    float acc = 0.f;
    for (int k = 0; k < 125; k++) {
        int t = t0 + k;
        acc += awr[t] * hp[(size_t)(b * 1000 + t) * 512 + e];
    }
    atomicAdd(&ws[OFF_CTX + b * 512 + e], acc);
}

// ---------------- per-step gate partials ----------------
// combined K: [0,1024)=embed(token), [1024,1536)=ctx, [1536,2560)=z
// grid = (kc 10) x (ntile 64); block 256
__global__ __launch_bounds__(256) void k_gates(const float* __restrict__ wih,
                                               const float* __restrict__ whh,
                                               const float* __restrict__ embed,
                                               const int* __restrict__ ys,
                                               float* ws, int step) {
    __shared__ float xs[256][36]; // [k][b], padded
    int kc = blockIdx.x >> 6;  // 0..9
    int nt = blockIdx.x & 63;
    int n0 = nt * 64;
    int tid = threadIdx.x;
    for (int i = tid; i < 8192; i += 256) {
        int b = i >> 8, k = i & 255;
        float v;
        if (kc < 4) {
            int tok = (step == 0) ? SOS_ : ys[b * 100 + step - 1];
            v = embed[(size_t)tok * 1024 + kc * 256 + k];
        } else if (kc < 6) {
            v = ws[OFF_CTX + b * 512 + (kc - 4) * 256 + k];
        } else {
            v = ws[OFF_Z + b * 1024 + (kc - 6) * 256 + k];
        }
        xs[k][b] = v;
    }
    __syncthreads();
    int nh = tid & 31, bg = tid >> 5; // bg covers b = bg*4 .. +3
    const float* w0;
    const float* w1;
    if (kc < 6) {
        w0 = wih + (size_t)(n0 + nh) * 1536 + kc * 256;
        w1 = wih + (size_t)(n0 + nh + 32) * 1536 + kc * 256;
    } else {
        w0 = whh + (size_t)(n0 + nh) * 1024 + (kc - 6) * 256;
        w1 = whh + (size_t)(n0 + nh + 32) * 1024 + (kc - 6) * 256;
    }
    float acc0[4] = {}, acc1[4] = {};
    #pragma unroll 8
    for (int k = 0; k < 256; k++) {
        float4 xv = *(const float4*)&xs[k][bg << 2];
        float a = w0[k], c = w1[k];
        acc0[0] += xv.x * a; acc0[1] += xv.y * a; acc0[2] += xv.z * a; acc0[3] += xv.w * a;
        acc1[0] += xv.x * c; acc1[1] += xv.y * c; acc1[2] += xv.z * c; acc1[3] += xv.w * c;
    }
    float* gp = ws + OFF_GP + (size_t)(kc * 32 + (bg << 2)) * 4096;
    #pragma unroll
    for (int j = 0; j < 4; j++) {
        gp[(size_t)j * 4096 + n0 + nh] = acc0[j];
        gp[(size_t)j * 4096 + n0 + nh + 32] = acc1[j];
    }
}

// ---------------- per-step LSTM elementwise ----------------
__global__ __launch_bounds__(256) void k_lstm(const float* __restrict__ bih,
                                              const float* __restrict__ bhh,
                                              float* ws, int step) {
    int id = blockIdx.x * 256 + threadIdx.x; // 0..32767
    int b = id >> 10, d = id & 1023;
    float gi = bih[d] + bhh[d];
    float gf = bih[1024 + d] + bhh[1024 + d];
    float gg = bih[2048 + d] + bhh[2048 + d];
    float go = bih[3072 + d] + bhh[3072 + d];
    const float* gp = ws + OFF_GP;
    #pragma unroll
    for (int kc = 0; kc < 10; kc++) {
        const float* r = gp + (size_t)(kc * 32 + b) * 4096;
        gi += r[d];
        gf += r[1024 + d];
        gg += r[2048 + d];
        go += r[3072 + d];
    }
    float c_old = ws[OFF_C + id];
    float si = 1.f / (1.f + expf(-gi));
    float sf = 1.f / (1.f + expf(-gf));
    float so = 1.f / (1.f + expf(-go));
    float cn = sf * c_old + si * tanhf(gg);
    float h = so * tanhf(cn);
    ws[OFF_C + id] = cn;
    ws[OFF_Z + id] = h;
    ws[OFF_ZALL + ((size_t)step * 32 + b) * 1024 + d] = h;
}

// ---------------- final: out[b,o,v] = zall[o,b,:] @ w_out[v,:] + b_out[v] ----------------
// M=3232 (o*32+b), N=5000, K=1024
__global__ __launch_bounds__(256) void k_out(const float* __restrict__ zall,
                                             const float* __restrict__ wo,
                                             const float* __restrict__ bo,
                                             float* __restrict__ out) {
    __shared__ float As[64][68];
    __shared__ float Bs[64][68];
    int m0 = blockIdx.y * 64, n0 = blockIdx.x * 64;
    int tid = threadIdx.x;
    int tr = tid >> 4, tc = tid & 15;
    float acc[4][4] = {};
    for (int k0 = 0; k0 < 1024; k0 += 64) {
        for (int i = tid; i < 1024; i += 256) {
            int m = i >> 4, kq = (i & 15) << 2;
            int gm = m0 + m;
            float4 v = (gm < 3232) ? *(const float4*)&zall[(size_t)gm * 1024 + k0 + kq]
                                   : make_float4(0.f, 0.f, 0.f, 0.f);
            As[kq + 0][m] = v.x; As[kq + 1][m] = v.y; As[kq + 2][m] = v.z; As[kq + 3][m] = v.w;
            int gn = n0 + m;
            float4 w = (gn < 5000) ? *(const float4*)&wo[(size_t)gn * 1024 + k0 + kq]
                                   : make_float4(0.f, 0.f, 0.f, 0.f);
            Bs[kq + 0][m] = w.x; Bs[kq + 1][m] = w.y; Bs[kq + 2][m] = w.z; Bs[kq + 3][m] = w.w;
        }
        __syncthreads();
        #pragma unroll 16
        for (int kk = 0; kk < 64; ++kk) {
            float4 av = *(const float4*)&As[kk][tr << 2];
            float4 bv = *(const float4*)&Bs[kk][tc << 2];
            float a[4] = {av.x, av.y, av.z, av.w};
            float b[4] = {bv.x, bv.y, bv.z, bv.w};
            #pragma unroll
            for (int i = 0; i < 4; i++)
                #pragma unroll
                for (int j = 0; j < 4; j++) acc[i][j] += a[i] * b[j];
        }
        __syncthreads();
    }
    #pragma unroll
    for (int i = 0; i < 4; i++) {
        int m = m0 + (tr << 2) + i;
        if (m >= 3232) continue;
        int b = m & 31, o = m >> 5;
        #pragma unroll
        for (int j = 0; j < 4; j++) {
            int v = n0 + (tc << 2) + j;
            if (v < 5000)
                out[((size_t)b * 101 + o) * 5000 + v] = acc[i][j] + bo[v];
        }
    }
}

extern "C" void kernel_launch(void* const* d_in, const int* in_sizes, int n_in,
                              void* d_out, int out_size, void* d_ws, size_t ws_size,
                              hipStream_t stream) {
    const float* hpad   = (const float*)d_in[0];
    const int*   ys     = (const int*)d_in[1];
    const float* w_enc  = (const float*)d_in[2];
    const float* b_enc  = (const float*)d_in[3];
    const float* w_dec  = (const float*)d_in[4];
    const float* w_att  = (const float*)d_in[5];
    const float* w_conv = (const float*)d_in[6];
    const float* w_gvec = (const float*)d_in[7];
    const float* b_gvec = (const float*)d_in[8];
    const float* embed  = (const float*)d_in[9];
    const float* w_ih   = (const float*)d_in[10];
    const float* w_hh   = (const float*)d_in[11];
    const float* b_ih   = (const float*)d_in[12];
    const float* b_hh   = (const float*)d_in[13];
    const float* w_out  = (const float*)d_in[14];
    const float* b_out  = (const float*)d_in[15];
    float* ws  = (float*)d_ws;
    float* out = (float*)d_out;

    k_init<<<128, 256, 0, stream>>>(ws);
    k_pre<<<dim3(8, 500), 256, 0, stream>>>(hpad, w_enc, b_enc, ws + OFF_PRE);

    for (int step = 0; step < OLEN_; ++step) {
        k_prep<<<4096 + 1250, 256, 0, stream>>>(w_dec, w_conv, ws);
        k_energy<<<8000, 256, 0, stream>>>(w_att, w_gvec, b_gvec, ws);
        k_softmax<<<32, 256, 0, stream>>>(ws);
        k_ctx<<<256, 512, 0, stream>>>(hpad, ws);
        k_gates<<<640, 256, 0, stream>>>(w_ih, w_hh, embed, ys, ws, step);
        k_lstm<<<128, 256, 0, stream>>>(b_ih, b_hh, ws, step);
    }

    k_out<<<dim3(79, 51), 256, 0, stream>>>(ws + OFF_ZALL, w_out, b_out, out);
}

// Round 2
// 10910.903 us; speedup vs baseline: 1.4791x; 1.4791x over previous
//
#include <hip/hip_runtime.h>
#include <math.h>

// Problem constants
#define B_    32
#define T_    1000
#define E_    512
#define D_    1024
#define A_    512
#define C_    10
#define F_    100
#define ODIM_ 5000
#define OLEN_ 101
#define SOS_  4998

// ---- workspace layout (float offsets) ---- (unchanged from round 0: 85.9 MB)
#define OFF_PRE   0u
#define N_PRE     (32u*1000u*512u)          // 16,384,000
#define OFF_DEC   (OFF_PRE + N_PRE)         // [B][A]
#define N_DEC     (32u*512u)
#define OFF_CONV  (OFF_DEC + N_DEC)         // [B][C][T]
#define N_CONVB   (32u*10u*1000u)
#define OFF_EB    (OFF_CONV + N_CONVB)      // [B][T] energies
#define N_EB      (32u*1000u)
#define OFF_AW    (OFF_EB + N_EB)           // [B][T] attention weights
#define OFF_CTX   (OFF_AW + N_EB)           // [B][E]
#define N_CTX     (32u*512u)
#define OFF_GP    (OFF_CTX + N_CTX)         // [10][B][4096] gate partials
#define N_GP      (10u*32u*4096u)
#define OFF_Z     (OFF_GP + N_GP)           // [B][D]
#define N_Z       (32u*1024u)
#define OFF_C     (OFF_Z + N_Z)             // [B][D]
#define OFF_ZALL  (OFF_C + N_Z)             // [101][B][D]

// ---- fast transcendentals (hw v_exp_f32 / v_rcp_f32; err ~1e-7 rel) ----
__device__ __forceinline__ float fast_tanh(float x) {
    float cx = fminf(8.f, fmaxf(-8.f, x));
    float e = __expf(2.f * cx);
    return (e - 1.f) * __builtin_amdgcn_rcpf(e + 1.f);
}
__device__ __forceinline__ float fast_sigmoid(float x) {
    float cx = fminf(30.f, fmaxf(-30.f, x));
    return __builtin_amdgcn_rcpf(1.f + __expf(-cx));
}

// ---------------- init: z=0, c=0, aw=1/T ----------------
__global__ __launch_bounds__(256) void k_init(float* ws) {
    int i = blockIdx.x * 256 + threadIdx.x;
    if (i < (int)N_Z) { ws[OFF_Z + i] = 0.f; ws[OFF_C + i] = 0.f; }
    if (i < (int)N_EB) ws[OFF_AW + i] = 1.0f / (float)T_;
}

// ---------------- pre = hpad @ w_enc^T + b_enc ----------------
__global__ __launch_bounds__(256) void k_pre(const float* __restrict__ hp,
                                             const float* __restrict__ we,
                                             const float* __restrict__ be,
                                             float* __restrict__ pre) {
    __shared__ float As[64][68];
    __shared__ float Bs[64][68];
    int m0 = blockIdx.y * 64, n0 = blockIdx.x * 64;
    int tid = threadIdx.x;
    int tr = tid >> 4, tc = tid & 15;
    float acc[4][4] = {};
    for (int k0 = 0; k0 < 512; k0 += 64) {
        for (int i = tid; i < 1024; i += 256) {
            int m = i >> 4, kq = (i & 15) << 2;
            float4 v = *(const float4*)&hp[(size_t)(m0 + m) * 512 + k0 + kq];
            As[kq + 0][m] = v.x; As[kq + 1][m] = v.y; As[kq + 2][m] = v.z; As[kq + 3][m] = v.w;
            float4 w = *(const float4*)&we[(size_t)(n0 + m) * 512 + k0 + kq];
            Bs[kq + 0][m] = w.x; Bs[kq + 1][m] = w.y; Bs[kq + 2][m] = w.z; Bs[kq + 3][m] = w.w;
        }
        __syncthreads();
        #pragma unroll 16
        for (int kk = 0; kk < 64; ++kk) {
            float4 av = *(const float4*)&As[kk][tr << 2];
            float4 bv = *(const float4*)&Bs[kk][tc << 2];
            float a[4] = {av.x, av.y, av.z, av.w};
            float b[4] = {bv.x, bv.y, bv.z, bv.w};
            #pragma unroll
            for (int i = 0; i < 4; i++)
                #pragma unroll
                for (int j = 0; j < 4; j++) acc[i][j] += a[i] * b[j];
        }
        __syncthreads();
    }
    #pragma unroll
    for (int i = 0; i < 4; i++) {
        int m = m0 + (tr << 2) + i;
        int n = n0 + (tc << 2);
        float4 o;
        o.x = acc[i][0] + be[n + 0];
        o.y = acc[i][1] + be[n + 1];
        o.z = acc[i][2] + be[n + 2];
        o.w = acc[i][3] + be[n + 3];
        *(float4*)&pre[(size_t)m * 512 + n] = o;
    }
}

// ---------------- per-step: dec = z @ w_dec^T ; conv (rolling window) ----------------
// blocks [0,1024): dec (4 waves each). blocks [1024,1344): conv, b=blk/10, c=blk%10.
__global__ __launch_bounds__(256) void k_prep(const float* __restrict__ wdec,
                                              const float* __restrict__ wconv,
                                              float* ws) {
    int tid = threadIdx.x;
    if (blockIdx.x < 1024) {
        int gw = blockIdx.x * 4 + (tid >> 6);
        int lane = tid & 63;
        int b = gw >> 9, a = gw & 511;
        const float4* wr = (const float4*)(wdec + (size_t)a * 1024);
        const float4* zr = (const float4*)(ws + OFF_Z + b * 1024);
        float acc = 0.f;
        #pragma unroll
        for (int i = 0; i < 4; i++) {
            float4 w4 = wr[i * 64 + lane];
            float4 z4 = zr[i * 64 + lane];
            acc += w4.x * z4.x + w4.y * z4.y + w4.z * z4.z + w4.w * z4.w;
        }
        #pragma unroll
        for (int off = 32; off > 0; off >>= 1) acc += __shfl_xor(acc, off, 64);
        if (lane == 0) ws[OFF_DEC + b * 512 + a] = acc;
    } else {
        int blk = blockIdx.x - 1024;   // 0..319
        int b = blk / 10, c = blk - b * 10;
        if (tid >= 250) return;
        int t = tid * 4;
        const float* ar = ws + OFF_AW + b * 1000;
        const float* wc = wconv + c * 201;
        float a0, a1, a2, a3;
        a0 = (t - 100 >= 0) ? ar[t - 100] : 0.f;
        a1 = (t -  99 >= 0) ? ar[t -  99] : 0.f;
        a2 = (t -  98 >= 0) ? ar[t -  98] : 0.f;
        a3 = (t -  97 >= 0) ? ar[t -  97] : 0.f;
        float c0 = 0.f, c1 = 0.f, c2 = 0.f, c3 = 0.f;
        #pragma unroll 4
        for (int j = 0; j < 201; ++j) {
            float w = wc[j];
            c0 += a0 * w; c1 += a1 * w; c2 += a2 * w; c3 += a3 * w;
            a0 = a1; a1 = a2; a2 = a3;
            int ni = t + j - 96;
            a3 = (ni >= 0 && ni < 1000) ? ar[ni] : 0.f;
        }
        float* o = ws + OFF_CONV + (size_t)(b * 10 + c) * 1000 + t;
        o[0] = c0; o[1] = c1; o[2] = c2; o[3] = c3;
    }
}

// ---------------- per-step energy e[b,t] ----------------
// 1 wave per block; block handles (b, 20 t's). watt/gvec/dec held in registers.
__global__ __launch_bounds__(64) void k_energy(const float* __restrict__ watt,
                                               const float* __restrict__ gvec,
                                               const float* __restrict__ bg,
                                               float* ws) {
    int b  = blockIdx.x / 50;
    int t0 = (blockIdx.x - b * 50) * 20;
    int lane = threadIdx.x;
    int a0 = lane * 4, a1 = 256 + lane * 4;
    float wr[8][10];
    #pragma unroll
    for (int i = 0; i < 4; i++)
        #pragma unroll
        for (int c = 0; c < 10; c++) {
            wr[i][c]     = watt[(a0 + i) * 10 + c];
            wr[4 + i][c] = watt[(a1 + i) * 10 + c];
        }
    float4 d0 = *(const float4*)&ws[OFF_DEC + b * 512 + a0];
    float4 d1 = *(const float4*)&ws[OFF_DEC + b * 512 + a1];
    float4 g0 = *(const float4*)&gvec[a0];
    float4 g1 = *(const float4*)&gvec[a1];
    float dc[8] = {d0.x, d0.y, d0.z, d0.w, d1.x, d1.y, d1.z, d1.w};
    float gv[8] = {g0.x, g0.y, g0.z, g0.w, g1.x, g1.y, g1.z, g1.w};
    float bgv = bg[0];
    const float* convb = ws + OFF_CONV + b * 10000;
    for (int it = 0; it < 20; ++it) {
        int t = t0 + it;
        const float* pr = ws + OFF_PRE + (size_t)(b * 1000 + t) * 512;
        float4 p0 = *(const float4*)&pr[a0];
        float4 p1 = *(const float4*)&pr[a1];
        float cv[10];
        #pragma unroll
        for (int c = 0; c < 10; c++) cv[c] = convb[c * 1000 + t];
        float pa[8] = {p0.x, p0.y, p0.z, p0.w, p1.x, p1.y, p1.z, p1.w};
        float acc = 0.f;
        #pragma unroll
        for (int i = 0; i < 8; i++) {
            float s = pa[i] + dc[i];
            #pragma unroll
            for (int c = 0; c < 10; c++) s += cv[c] * wr[i][c];
            acc += gv[i] * fast_tanh(s);
        }
        #pragma unroll
        for (int off = 32; off > 0; off >>= 1) acc += __shfl_xor(acc, off, 64);
        if (lane == 0) ws[OFF_EB + b * 1000 + t] = acc + bgv;
    }
}

// ---------------- per-step softmax over T (+ zero ctx) ----------------
__global__ __launch_bounds__(256) void k_softmax(float* ws) {
    int b = blockIdx.x, tid = threadIdx.x;
    ws[OFF_CTX + b * 512 + tid] = 0.f;
    ws[OFF_CTX + b * 512 + 256 + tid] = 0.f;
    __shared__ float red[256];
    const float* e = ws + OFF_EB + b * 1000;
    float s[4];
    float m = -1e30f;
    #pragma unroll
    for (int j = 0; j < 4; j++) {
        int t = tid + j * 256;
        s[j] = (t < 1000) ? 2.0f * e[t] : -1e30f;
        m = fmaxf(m, s[j]);
    }
    red[tid] = m; __syncthreads();
    for (int off = 128; off > 0; off >>= 1) {
        if (tid < off) red[tid] = fmaxf(red[tid], red[tid + off]);
        __syncthreads();
    }
    m = red[0]; __syncthreads();
    float p[4], sum = 0.f;
    #pragma unroll
    for (int j = 0; j < 4; j++) {
        int t = tid + j * 256;
        p[j] = (t < 1000) ? __expf(s[j] - m) : 0.f;
        sum += p[j];
    }
    red[tid] = sum; __syncthreads();
    for (int off = 128; off > 0; off >>= 1) {
        if (tid < off) red[tid] += red[tid + off];
        __syncthreads();
    }
    float inv = __builtin_amdgcn_rcpf(red[0]);
    #pragma unroll
    for (int j = 0; j < 4; j++) {
        int t = tid + j * 256;
        if (t < 1000) ws[OFF_AW + b * 1000 + t] = p[j] * inv;
    }
}

// ---------------- per-step ctx[b,e] = sum_t aw[b,t]*hpad[b,t,e] ----------------
// grid = 32 b x 32 tsplit; 128 threads (float4 over e)
__global__ __launch_bounds__(128) void k_ctx(const float* __restrict__ hp, float* ws) {
    int b = blockIdx.x >> 5, ts = blockIdx.x & 31;
    int e4 = threadIdx.x;
    const float* awr = ws + OFF_AW + b * 1000;
    const float4* hp4 = (const float4*)hp;
    int t0 = ts * 32;
    int t1 = t0 + 32; if (t1 > 1000) t1 = 1000;
    float4 acc = make_float4(0.f, 0.f, 0.f, 0.f);
    for (int t = t0; t < t1; ++t) {
        float w = awr[t];
        float4 h = hp4[(size_t)(b * 1000 + t) * 128 + e4];
        acc.x += w * h.x; acc.y += w * h.y; acc.z += w * h.z; acc.w += w * h.w;
    }
    float* cx = ws + OFF_CTX + b * 512 + e4 * 4;
    atomicAdd(cx + 0, acc.x); atomicAdd(cx + 1, acc.y);
    atomicAdd(cx + 2, acc.z); atomicAdd(cx + 3, acc.w);
}

// ---------------- per-step gate partials (tiled GEMM, LDS-staged) ----------------
// C[b][n] = sum_k x[b][k]*W[n][k], x = [ey(1024) | ctx(512) | z(1024)], K=2560
// grid = 64 ntiles * 10 ksplit; block 128. Each block: n-tile 64, K-range 256 (8 chunks of 32).
__global__ __launch_bounds__(128) void k_gates(const float* __restrict__ wih,
                                               const float* __restrict__ whh,
                                               const float* __restrict__ embed,
                                               const int* __restrict__ ys,
                                               float* ws, int step) {
    __shared__ float wlds[32][68];
    __shared__ float xs[32][36];
    int nt = blockIdx.x & 63;
    int ks = blockIdx.x >> 6;          // 0..9
    int n0 = nt * 64;
    int tid = threadIdx.x;
    int nq = tid & 15, bq = tid >> 4;  // nq: 16 n-groups of 4; bq: 8 b-groups of 4
    float acc[4][4] = {};
    for (int kc = 0; kc < 8; ++kc) {
        int k0 = ks * 256 + kc * 32;   // 32-chunk, never straddles 1024/1536
        // stage W[n0..n0+63][k0..k0+31] transposed into wlds[k][n]
        {
            int r = tid >> 1, h = tid & 1;
            int gn = n0 + r;
            const float* wrow = (k0 < 1536)
                ? (wih + (size_t)gn * 1536 + k0 + h * 16)
                : (whh + (size_t)gn * 1024 + (k0 - 1536) + h * 16);
            #pragma unroll
            for (int j = 0; j < 4; ++j) {
                float4 v = *(const float4*)&wrow[j * 4];
                int kb = h * 16 + j * 4;
                wlds[kb + 0][r] = v.x; wlds[kb + 1][r] = v.y;
                wlds[kb + 2][r] = v.z; wlds[kb + 3][r] = v.w;
            }
        }
        // stage x[b][k0..k0+31] into xs[k][b]
        {
            int b = tid >> 2, q = tid & 3;
            int tok = (step == 0) ? SOS_ : ys[b * 100 + step - 1];
            #pragma unroll
            for (int j = 0; j < 2; ++j) {
                int kk = k0 + q * 8 + j * 4;
                float4 v;
                if (kk < 1024)       v = *(const float4*)&embed[(size_t)tok * 1024 + kk];
                else if (kk < 1536)  v = *(const float4*)&ws[OFF_CTX + b * 512 + kk - 1024];
                else                 v = *(const float4*)&ws[OFF_Z + b * 1024 + kk - 1536];
                int kb = q * 8 + j * 4;
                xs[kb + 0][b] = v.x; xs[kb + 1][b] = v.y;
                xs[kb + 2][b] = v.z; xs[kb + 3][b] = v.w;
            }
        }
        __syncthreads();
        #pragma unroll 8
        for (int kk = 0; kk < 32; ++kk) {
            float4 wv = *(const float4*)&wlds[kk][nq * 4];
            float4 xv = *(const float4*)&xs[kk][bq * 4];
            float wa[4] = {wv.x, wv.y, wv.z, wv.w};
            float xa[4] = {xv.x, xv.y, xv.z, xv.w};
            #pragma unroll
            for (int i = 0; i < 4; i++)
                #pragma unroll
                for (int j = 0; j < 4; j++) acc[i][j] += wa[i] * xa[j];
        }
        __syncthreads();
    }
    float* gp = ws + OFF_GP + (size_t)(ks * 32 + bq * 4) * 4096 + n0 + nq * 4;
    #pragma unroll
    for (int j = 0; j < 4; j++)
        #pragma unroll
        for (int i = 0; i < 4; i++)
            gp[(size_t)j * 4096 + i] = acc[i][j];
}

// ---------------- per-step LSTM elementwise ----------------
__global__ __launch_bounds__(256) void k_lstm(const float* __restrict__ bih,
                                              const float* __restrict__ bhh,
                                              float* ws, int step) {
    int id = blockIdx.x * 256 + threadIdx.x; // 0..32767
    int b = id >> 10, d = id & 1023;
    float gi = bih[d] + bhh[d];
    float gf = bih[1024 + d] + bhh[1024 + d];
    float gg = bih[2048 + d] + bhh[2048 + d];
    float go = bih[3072 + d] + bhh[3072 + d];
    const float* gp = ws + OFF_GP;
    #pragma unroll
    for (int kc = 0; kc < 10; kc++) {
        const float* r = gp + (size_t)(kc * 32 + b) * 4096;
        gi += r[d];
        gf += r[1024 + d];
        gg += r[2048 + d];
        go += r[3072 + d];
    }
    float c_old = ws[OFF_C + id];
    float si = fast_sigmoid(gi);
    float sf = fast_sigmoid(gf);
    float so = fast_sigmoid(go);
    float cn = sf * c_old + si * fast_tanh(gg);
    float h = so * fast_tanh(cn);
    ws[OFF_C + id] = cn;
    ws[OFF_Z + id] = h;
    ws[OFF_ZALL + ((size_t)step * 32 + b) * 1024 + d] = h;
}

// ---------------- final: out[b,o,v] = zall[o,b,:] @ w_out[v,:] + b_out[v] ----------------
__global__ __launch_bounds__(256) void k_out(const float* __restrict__ zall,
                                             const float* __restrict__ wo,
                                             const float* __restrict__ bo,
                                             float* __restrict__ out) {
    __shared__ float As[64][68];
    __shared__ float Bs[64][68];
    int m0 = blockIdx.y * 64, n0 = blockIdx.x * 64;
    int tid = threadIdx.x;
    int tr = tid >> 4, tc = tid & 15;
    float acc[4][4] = {};
    for (int k0 = 0; k0 < 1024; k0 += 64) {
        for (int i = tid; i < 1024; i += 256) {
            int m = i >> 4, kq = (i & 15) << 2;
            int gm = m0 + m;
            float4 v = (gm < 3232) ? *(const float4*)&zall[(size_t)gm * 1024 + k0 + kq]
                                   : make_float4(0.f, 0.f, 0.f, 0.f);
            As[kq + 0][m] = v.x; As[kq + 1][m] = v.y; As[kq + 2][m] = v.z; As[kq + 3][m] = v.w;
            int gn = n0 + m;
            float4 w = (gn < 5000) ? *(const float4*)&wo[(size_t)gn * 1024 + k0 + kq]
                                   : make_float4(0.f, 0.f, 0.f, 0.f);
            Bs[kq + 0][m] = w.x; Bs[kq + 1][m] = w.y; Bs[kq + 2][m] = w.z; Bs[kq + 3][m] = w.w;
        }
        __syncthreads();
        #pragma unroll 16
        for (int kk = 0; kk < 64; ++kk) {
            float4 av = *(const float4*)&As[kk][tr << 2];
            float4 bv = *(const float4*)&Bs[kk][tc << 2];
            float a[4] = {av.x, av.y, av.z, av.w};
            float b[4] = {bv.x, bv.y, bv.z, bv.w};
            #pragma unroll
            for (int i = 0; i < 4; i++)
                #pragma unroll
                for (int j = 0; j < 4; j++) acc[i][j] += a[i] * b[j];
        }
        __syncthreads();
    }
    #pragma unroll
    for (int i = 0; i < 4; i++) {
        int m = m0 + (tr << 2) + i;
        if (m >= 3232) continue;
        int b = m & 31, o = m >> 5;
        #pragma unroll
        for (int j = 0; j < 4; j++) {
            int v = n0 + (tc << 2) + j;
            if (v < 5000)
                out[((size_t)b * 101 + o) * 5000 + v] = acc[i][j] + bo[v];
        }
    }
}

extern "C" void kernel_launch(void* const* d_in, const int* in_sizes, int n_in,
                              void* d_out, int out_size, void* d_ws, size_t ws_size,
                              hipStream_t stream) {
    const float* hpad   = (const float*)d_in[0];
    const int*   ys     = (const int*)d_in[1];
    const float* w_enc  = (const float*)d_in[2];
    const float* b_enc  = (const float*)d_in[3];
    const float* w_dec  = (const float*)d_in[4];
    const float* w_att  = (const float*)d_in[5];
    const float* w_conv = (const float*)d_in[6];
    const float* w_gvec = (const float*)d_in[7];
    const float* b_gvec = (const float*)d_in[8];
    const float* embed  = (const float*)d_in[9];
    const float* w_ih   = (const float*)d_in[10];
    const float* w_hh   = (const float*)d_in[11];
    const float* b_ih   = (const float*)d_in[12];
    const float* b_hh   = (const float*)d_in[13];
    const float* w_out  = (const float*)d_in[14];
    const float* b_out  = (const float*)d_in[15];
    float* ws  = (float*)d_ws;
    float* out = (float*)d_out;

    k_init<<<128, 256, 0, stream>>>(ws);
    k_pre<<<dim3(8, 500), 256, 0, stream>>>(hpad, w_enc, b_enc, ws + OFF_PRE);

    for (int step = 0; step < OLEN_; ++step) {
        k_prep<<<1024 + 320, 256, 0, stream>>>(w_dec, w_conv, ws);
        k_energy<<<1600, 64, 0, stream>>>(w_att, w_gvec, b_gvec, ws);
        k_softmax<<<32, 256, 0, stream>>>(ws);
        k_ctx<<<1024, 128, 0, stream>>>(hpad, ws);
        k_gates<<<640, 128, 0, stream>>>(w_ih, w_hh, embed, ys, ws, step);
        k_lstm<<<128, 256, 0, stream>>>(b_ih, b_hh, ws, step);
    }

    k_out<<<dim3(79, 51), 256, 0, stream>>>(ws + OFF_ZALL, w_out, b_out, out);
}